// Round 11
// baseline (134.081 us; speedup 1.0000x reference)
//
#include <hip/hip_runtime.h>
#include <math.h>

#define HW_   128
#define CIN_  64
#define IMG_  (HW_ * HW_)       // 16384

// 2 output rows x 32 output cols per block
#define TR_    6                // tile rows  [h0-2 .. h0+3]
#define TC_    40               // tile cols  [w0-4 .. w0+35]
#define PIT_   32               // dwords per pixel (64ch bf16, no pad)
                                // bank conflicts handled by chunk-XOR swizzle
#define TILEDW (TR_ * TC_ * PIT_)   // 7680 dw = 30720 B
#define NU_    (TR_ * 8 * 10)       // 480 staging units (r, cq, cc)

typedef short    s16x8 __attribute__((ext_vector_type(8)));
typedef float    f32x4 __attribute__((ext_vector_type(4)));
typedef float    f32x2 __attribute__((ext_vector_type(2)));
typedef unsigned u32x4 __attribute__((ext_vector_type(4)));

__device__ __forceinline__ short f2bf(float f) {
  union { float f; unsigned i; } v; v.f = f;
  unsigned r = (v.i + 0x7fffu + ((v.i >> 16) & 1u)) >> 16;   // RNE
  return (short)r;
}

#if defined(__has_builtin)
#if __has_builtin(__builtin_amdgcn_cvt_pk_bf16_f32)
#define HAVE_CVT_PK_BF16 1
#endif
#endif

// pack two f32 -> bf16 pair (lo=a, hi=b)
__device__ __forceinline__ unsigned PK2(float a, float b) {
#ifdef HAVE_CVT_PK_BF16
  typedef __bf16 bf16x2_t __attribute__((ext_vector_type(2)));
  union { bf16x2_t v; unsigned u; } cv;
  cv.v = __builtin_amdgcn_cvt_pk_bf16_f32(a, b);
  return cv.u;
#else
  union { float f; unsigned u; } ua, ub; ua.f = a; ub.f = b;
  unsigned ra = ua.u + 0x7fffu + ((ua.u >> 16) & 1u);
  unsigned rb = ub.u + 0x7fffu + ((ub.u >> 16) & 1u);
  return __builtin_amdgcn_perm(rb, ra, 0x07060302u);
#endif
}

// dirty-hi f32x2 unpack of a bf16 pair: elem0 exact (d<<16), elem1 keeps the
// junk low 16 mantissa bits (rel err ~2^-16, far below the 2^-9 bf16 repack
// rounding). 1 VALU op per dword; blend chains on f32x2 emit v_pk_fma_f32.
__device__ __forceinline__ f32x2 up2d(unsigned d) {
  union { unsigned u; float f; } lo, hi;
  lo.u = d << 16; hi.u = d;
  return (f32x2){lo.f, hi.f};
}

// ws layout (bytes):
//   [0,     36864)  wOf bf16 [j:9][ks:2][q:4][m:32][i:8]  (A-frag order, m>=27 zero)
//   [36864, 110592) wA  bf16 [j:9][ks:2][q:4][o:64][i:8]  (A-frag order)

__global__ __launch_bounds__(256) void wprep(const float* __restrict__ w_off,
                                             const float* __restrict__ w_conv,
                                             short* __restrict__ wOf,
                                             short* __restrict__ wA) {
  int t = blockIdx.x * 256 + threadIdx.x;
  if (t < 36864) {
    int i = t & 7, o = (t >> 3) & 63, q = (t >> 9) & 3, ks = (t >> 11) & 1, j = t >> 12;
    int c = ks * 32 + q * 8 + i;
    wA[t] = f2bf(w_conv[o * 576 + c * 9 + j]);
  }
  if (t < 18432) {
    int i = t & 7, m = (t >> 3) & 31, q = (t >> 8) & 3, ks = (t >> 10) & 1, j = t >> 11;
    int c = ks * 32 + q * 8 + i;
    wOf[t] = (m < 27) ? f2bf(w_off[(m * 64 + c) * 9 + j]) : (short)0;
  }
}

// Per-tap sampling state (coords, weights, clamped swizzled LDS addresses).
struct Samp {
  float u00, u01, u10, u11;
  int   x0, y0;
  int   boff, s0, s1;
  bool  intile;
};

__device__ __forceinline__ Samp mkcoord(int j, const float* oall,
                                        int w, int h, int h0, int w0, int q) {
  Samp s;
  float o1 = oall[j], o2 = oall[9 + j], mk = oall[18 + j];
  float pxf = o1 + (float)(w + (j % 3) - 1);
  float pyf = o2 + (float)(h + (j / 3) - 1);
  float fx = floorf(pxf), fy = floorf(pyf);
  s.x0 = (int)fx; s.y0 = (int)fy;
  float ax = pxf - fx, ay = pyf - fy;
  float bx = 1.f - ax, by = 1.f - ay;
  // validity factorizes per-axis: zero the axis weight instead of the product
  bx = (s.x0 >= 0  && s.x0 < HW_)     ? bx : 0.f;
  ax = (s.x0 >= -1 && s.x0 < HW_ - 1) ? ax : 0.f;
  by = (s.y0 >= 0  && s.y0 < HW_)     ? by : 0.f;
  ay = (s.y0 >= -1 && s.y0 < HW_ - 1) ? ay : 0.f;
  float bym = by * mk, aym = ay * mk;
  s.u00 = bym * bx; s.u01 = bym * ax;
  s.u10 = aym * bx; s.u11 = aym * ax;
  s.intile = (o1 >= -1.f) && (o1 < 1.f) && (o2 >= -1.f) && (o2 < 1.f);
  // clamped base: no-op for intile lanes (r0 in [0,4], c0 in [2,36]);
  // keeps prefetch addresses in-bounds for fallback lanes (values unused).
  int r0 = min(max(s.y0 - (h0 - 2), 0), TR_ - 2);
  int c0 = min(max(s.x0 - (w0 - 4), 0), TC_ - 2);
  s.boff = (r0 * TC_ + c0) * PIT_;
  s.s0 = (q ^ (c0 & 7)) << 2;
  s.s1 = (q ^ ((c0 + 1) & 7)) << 2;
  return s;
}

struct Ld { u32x4 A00, A01, A10, A11, B00, B01, B10, B11; };

__device__ __forceinline__ Ld ldtile(const unsigned* lds_, const Samp& s) {
  Ld d;
  const unsigned* b00 = lds_ + s.boff;
  d.A00 = *(const u32x4*)(b00 + s.s0);
  d.A01 = *(const u32x4*)(b00 + PIT_ + s.s1);
  d.A10 = *(const u32x4*)(b00 + TC_ * PIT_ + s.s0);
  d.A11 = *(const u32x4*)(b00 + TC_ * PIT_ + PIT_ + s.s1);
  d.B00 = *(const u32x4*)(b00 + (s.s0 ^ 16));
  d.B01 = *(const u32x4*)(b00 + PIT_ + (s.s1 ^ 16));
  d.B10 = *(const u32x4*)(b00 + TC_ * PIT_ + (s.s0 ^ 16));
  d.B11 = *(const u32x4*)(b00 + TC_ * PIT_ + PIT_ + (s.s1 ^ 16));
  return d;
}

// Fully fused: stage f32 NCHW -> bf16 NHWC halo tile in SWIZZLED LDS
// (zero-filled OOB, one barrier), offset conv (MFMA), shuffle-exchange
// offsets, LDS-gather sampling + MFMA GEMM (f32 global fallback for |o|>=1).
// Round-11 = round-10 + phase-3 SOFTWARE PIPELINE: issue j+1's 8 ds_read_b128
// (ping-pong register sets, fully unrolled -> SSA renames) before blending j,
// hiding the ~120cy LDS latency under the blend+MFMA. The Ld set is fully
// defined BEFORE the intile/fallback branch (avoids the r8/r9 partial-def
// scratch demotion). waves_per_eu(3) raises the VGPR cap to ~170 so the
// two in-flight Ld sets (+64 VGPR) cannot spill; measured occupancy was
// ~10.5 waves/CU, below the new 12-wave ceiling, so no occupancy loss.
__global__ __launch_bounds__(256)
__attribute__((amdgpu_waves_per_eu(3)))
void dfuse(const float* __restrict__ x,
           const short* __restrict__ wOf,
           const float* __restrict__ b_off,
           const short* __restrict__ wA,
           float* __restrict__ out) {
  __shared__ __align__(16) unsigned lds_[TILEDW];

  int bi  = blockIdx.x & 7;        // XCD-aligned image index
  int tid = blockIdx.x >> 3;       // 0..255 tile within image
  int h0  = (tid >> 2) << 1;       // 0,2,..,126
  int w0  = (tid & 3) << 5;        // 0,32,64,96
  int t   = threadIdx.x;
  int wv  = t >> 6, l = t & 63;
  int col = l & 15, q = l >> 4;
  int px_local = wv * 16 + col;    // 0..63
  int rl  = px_local >> 5;         // local row 0..1
  int cl  = px_local & 31;         // local col 0..31
  int h   = h0 + rl;
  int w   = w0 + cl;
  int p   = h * HW_ + w;

  const float* xB = x + (size_t)bi * (CIN_ * IMG_);

  // ---- stage halo tile: rows h0-2..h0+3, cols w0-4..w0+35, 64 ch bf16 ----
  // unit u: cc = u%10 (4-px chunk), cq = (u/10)%8 (channels 8cq..8cq+7),
  // r = u/80. Unit A = t, unit B = t+256 (first 224 threads only).
  // Write: one ds_write_b128 per pixel at swizzled chunk (cq ^ (c&7)).
  {
    f32x4 L0a[4], L1a[4], L0b[4], L1b[4];
    int baseA, baseB, swA, swB;
    unsigned ma, mb;
    {
      int u = t;
      int cc = u % 10, cq = (u / 10) & 7, r = u / 80;
      int y  = h0 - 2 + r;
      int ys = min(max(y, 0), HW_ - 1);
      int xg0 = w0 - 4 + cc * 4;
      int xs  = min(max(xg0, 0), HW_ - 4);             // 16B-aligned
      ma = ((y >= 0) && (y < HW_) && (xg0 >= 0) && (xg0 < HW_)) ? 0xffffffffu : 0u;
      const float* s0 = xB + (size_t)(8 * cq) * IMG_ + ys * HW_ + xs;
#pragma unroll
      for (int i = 0; i < 4; ++i) {
        L0a[i] = *(const f32x4*)(s0 + (2 * i) * IMG_);
        L1a[i] = *(const f32x4*)(s0 + (2 * i + 1) * IMG_);
      }
      baseA = (r * TC_ + cc * 4) * PIT_;
      swA   = cq ^ ((cc & 1) << 2);          // ^ pxi applied per store
    }
    bool hasB = (t + 256) < NU_;
    {
      int u = hasB ? (t + 256) : 0;
      int cc = u % 10, cq = (u / 10) & 7, r = u / 80;
      int y  = h0 - 2 + r;
      int ys = min(max(y, 0), HW_ - 1);
      int xg0 = w0 - 4 + cc * 4;
      int xs  = min(max(xg0, 0), HW_ - 4);
      mb = ((y >= 0) && (y < HW_) && (xg0 >= 0) && (xg0 < HW_)) ? 0xffffffffu : 0u;
      const float* s0 = xB + (size_t)(8 * cq) * IMG_ + ys * HW_ + xs;
#pragma unroll
      for (int i = 0; i < 4; ++i) {
        L0b[i] = *(const f32x4*)(s0 + (2 * i) * IMG_);
        L1b[i] = *(const f32x4*)(s0 + (2 * i + 1) * IMG_);
      }
      baseB = (r * TC_ + cc * 4) * PIT_;
      swB   = cq ^ ((cc & 1) << 2);
    }
#pragma unroll
    for (int pxi = 0; pxi < 4; ++pxi) {
      u32x4 v;
#pragma unroll
      for (int i = 0; i < 4; ++i) v[i] = PK2(L0a[i][pxi], L1a[i][pxi]) & ma;
      *(u32x4*)(lds_ + baseA + pxi * PIT_ + ((swA ^ pxi) << 2)) = v;
    }
    if (hasB) {
#pragma unroll
      for (int pxi = 0; pxi < 4; ++pxi) {
        u32x4 v;
#pragma unroll
        for (int i = 0; i < 4; ++i) v[i] = PK2(L0b[i][pxi], L1b[i][pxi]) & mb;
        *(u32x4*)(lds_ + baseB + pxi * PIT_ + ((swB ^ pxi) << 2)) = v;
      }
    }
  }
  __syncthreads();

  // ---- phase 1: offset conv from tile (tile is zero-padded: no masking) ----
  float oall[32];
  {
    const short* wq_ = wOf + q * 256 + col * 8;
    f32x4 a0v = {0.f, 0.f, 0.f, 0.f};
    f32x4 a1v = {0.f, 0.f, 0.f, 0.f};
    f32x4 a0w = {0.f, 0.f, 0.f, 0.f};
    f32x4 a1w = {0.f, 0.f, 0.f, 0.f};
    const unsigned* tbp = lds_ + ((rl + 2) * TC_ + (cl + 4)) * PIT_;
#pragma unroll
    for (int j = 0; j < 9; ++j) {
      int dy = j / 3 - 1, dx = j % 3 - 1;
      int ca = (q ^ ((cl + 4 + dx) & 7)) << 2;
      const unsigned* pb = tbp + (dy * TC_ + dx) * PIT_;
      union { u32x4 u; s16x8 v; } B0, B1;
      B0.u = *(const u32x4*)(pb + ca);
      B1.u = *(const u32x4*)(pb + (ca ^ 16));
      const short* wj = wq_ + j * 2048;
      s16x8 a00 = *(const s16x8*)(wj);
      s16x8 a01 = *(const s16x8*)(wj + 128);
      s16x8 a10 = *(const s16x8*)(wj + 1024);
      s16x8 a11 = *(const s16x8*)(wj + 1024 + 128);
      a0v = __builtin_amdgcn_mfma_f32_16x16x32_bf16(a00, B0.v, a0v, 0, 0, 0);
      a1v = __builtin_amdgcn_mfma_f32_16x16x32_bf16(a01, B0.v, a1v, 0, 0, 0);
      a0w = __builtin_amdgcn_mfma_f32_16x16x32_bf16(a10, B1.v, a0w, 0, 0, 0);
      a1w = __builtin_amdgcn_mfma_f32_16x16x32_bf16(a11, B1.v, a1w, 0, 0, 0);
    }
    a0v += a0w;
    a1v += a1w;
    // bias + sigmoid by producer lanes, then wave-local shuffle exchange
    float myv[8];
#pragma unroll
    for (int r = 0; r < 4; ++r) myv[r] = a0v[r] + b_off[q * 4 + r];
#pragma unroll
    for (int r = 0; r < 4; ++r) {
      int ch = 16 + q * 4 + r;
      float bo = b_off[min(ch, 26)];
      float v = a1v[r] + bo;
      myv[4 + r] = (ch >= 18) ? (1.f / (1.f + __expf(-v))) : v;
    }
#pragma unroll
    for (int qq = 0; qq < 4; ++qq) {
      int src = qq * 16 + col;
#pragma unroll
      for (int r = 0; r < 4; ++r) {
        oall[qq * 4 + r]      = __shfl(myv[r], src);
        oall[16 + qq * 4 + r] = __shfl(myv[4 + r], src);
      }
    }
  }

  // ---- phase 3: LDS-gather sampling + MFMA GEMM (1-deep j-pipeline) ----
  f32x4 acc[4], accB[4];
#pragma unroll
  for (int ms = 0; ms < 4; ++ms) {
    acc[ms]  = (f32x4){0.f, 0.f, 0.f, 0.f};
    accB[ms] = (f32x4){0.f, 0.f, 0.f, 0.f};
  }

  const short* wqA = wA + q * 512 + col * 8;

  Samp s_cur = mkcoord(0, oall, w, h, h0, w0, q);
  Ld   c_cur = ldtile(lds_, s_cur);

#pragma unroll
  for (int j = 0; j < 9; ++j) {
    // prefetch j+1: coords + issue 8 ds_read_b128 before consuming j
    Samp s_nxt; Ld c_nxt;
    if (j < 8) {
      s_nxt = mkcoord(j + 1, oall, w, h, h0, w0, q);
      c_nxt = ldtile(lds_, s_nxt);
    }

    f32x2 U00 = {s_cur.u00, s_cur.u00}, U01 = {s_cur.u01, s_cur.u01};
    f32x2 U10 = {s_cur.u10, s_cur.u10}, U11 = {s_cur.u11, s_cur.u11};

    unsigned F0u[4], F1u[4];
    if (s_cur.intile) {
#pragma unroll
      for (int i = 0; i < 4; ++i) {
        f32x2 v0 = up2d(c_cur.A00[i]) * U00 + up2d(c_cur.A01[i]) * U01
                 + up2d(c_cur.A10[i]) * U10 + up2d(c_cur.A11[i]) * U11;
        F0u[i] = PK2(v0.x, v0.y);
        f32x2 v1 = up2d(c_cur.B00[i]) * U00 + up2d(c_cur.B01[i]) * U01
                 + up2d(c_cur.B10[i]) * U10 + up2d(c_cur.B11[i]) * U11;
        F1u[i] = PK2(v1.x, v1.y);
      }
    } else {
      // rare fallback: gather straight from f32 NCHW x (clamps only here)
      int x0 = s_cur.x0, y0 = s_cur.y0;
      float u00 = s_cur.u00, u01 = s_cur.u01, u10 = s_cur.u10, u11 = s_cur.u11;
      int xc0 = min(max(x0, 0), HW_ - 1), xc1 = min(max(x0 + 1, 0), HW_ - 1);
      int yc0 = min(max(y0, 0), HW_ - 1), yc1 = min(max(y0 + 1, 0), HW_ - 1);
      int g00 = yc0 * HW_ + xc0, g01 = yc0 * HW_ + xc1;
      int g10 = yc1 * HW_ + xc0, g11 = yc1 * HW_ + xc1;
      for (int hB = 0; hB < 2; ++hB) {
        for (int ii = 0; ii < 4; ++ii) {
          int c0i = hB * 32 + q * 8 + 2 * ii;
          const float* pc = xB + c0i * IMG_;
          const float* pd = pc + IMG_;
          float va = u00 * pc[g00] + u01 * pc[g01] + u10 * pc[g10] + u11 * pc[g11];
          float vb = u00 * pd[g00] + u01 * pd[g01] + u10 * pd[g10] + u11 * pd[g11];
          if (hB) F1u[ii] = PK2(va, vb); else F0u[ii] = PK2(va, vb);
        }
      }
    }

    union { unsigned u[4]; s16x8 v; } F0, F1;
#pragma unroll
    for (int i = 0; i < 4; ++i) { F0.u[i] = F0u[i]; F1.u[i] = F1u[i]; }

    const short* wj = wqA + j * 4096;
#pragma unroll
    for (int ms = 0; ms < 4; ++ms) {
      s16x8 a0 = *(const s16x8*)(wj + ms * 128);
      acc[ms] = __builtin_amdgcn_mfma_f32_16x16x32_bf16(a0, F0.v, acc[ms], 0, 0, 0);
    }
#pragma unroll
    for (int ms = 0; ms < 4; ++ms) {
      s16x8 a1 = *(const s16x8*)(wj + 2048 + ms * 128);
      accB[ms] = __builtin_amdgcn_mfma_f32_16x16x32_bf16(a1, F1.v, accB[ms], 0, 0, 0);
    }

    if (j < 8) { s_cur = s_nxt; c_cur = c_nxt; }
  }

  float* op = out + (size_t)bi * (CIN_ * IMG_) + p;
#pragma unroll
  for (int ms = 0; ms < 4; ++ms) {
    f32x4 r = acc[ms] + accB[ms];
#pragma unroll
    for (int rr = 0; rr < 4; ++rr)
      op[(ms * 16 + q * 4 + rr) * IMG_] = r[rr];
  }
}

extern "C" void kernel_launch(void* const* d_in, const int* in_sizes, int n_in,
                              void* d_out, int out_size, void* d_ws, size_t ws_size,
                              hipStream_t stream) {
  const float* x      = (const float*)d_in[0];
  const float* w_off  = (const float*)d_in[1];
  const float* b_off  = (const float*)d_in[2];
  const float* w_conv = (const float*)d_in[3];
  float* out = (float*)d_out;

  char* ws = (char*)d_ws;
  short* wOf = (short*)(ws);
  short* wA  = (short*)(ws + 36864);

  hipLaunchKernelGGL(wprep, dim3(144),  dim3(256), 0, stream, w_off, w_conv, wOf, wA);
  hipLaunchKernelGGL(dfuse, dim3(2048), dim3(256), 0, stream, x, wOf, b_off, wA, out);
}

// Round 12
// 127.835 us; speedup vs baseline: 1.0489x; 1.0489x over previous
//
#include <hip/hip_runtime.h>
#include <math.h>

#define HW_   128
#define CIN_  64
#define IMG_  (HW_ * HW_)       // 16384

// 4 output rows x 32 output cols per block (512 threads, 8 waves)
#define TR_    8                // tile rows  [h0-2 .. h0+5]
#define TC_    40               // tile cols  [w0-4 .. w0+35]
#define PIT_   32               // dwords per pixel (64ch bf16, no pad)
                                // bank conflicts handled by chunk-XOR swizzle
#define TILEDW (TR_ * TC_ * PIT_)   // 10240 dw = 40960 B -> 4 blocks/CU (= 32 waves/CU, HW max)
#define NU_    (TR_ * 8 * 10)       // 640 staging units (r, cq, cc)

typedef short    s16x8 __attribute__((ext_vector_type(8)));
typedef float    f32x4 __attribute__((ext_vector_type(4)));
typedef float    f32x2 __attribute__((ext_vector_type(2)));
typedef unsigned u32x4 __attribute__((ext_vector_type(4)));

__device__ __forceinline__ short f2bf(float f) {
  union { float f; unsigned i; } v; v.f = f;
  unsigned r = (v.i + 0x7fffu + ((v.i >> 16) & 1u)) >> 16;   // RNE
  return (short)r;
}

#if defined(__has_builtin)
#if __has_builtin(__builtin_amdgcn_cvt_pk_bf16_f32)
#define HAVE_CVT_PK_BF16 1
#endif
#endif

// pack two f32 -> bf16 pair (lo=a, hi=b)
__device__ __forceinline__ unsigned PK2(float a, float b) {
#ifdef HAVE_CVT_PK_BF16
  typedef __bf16 bf16x2_t __attribute__((ext_vector_type(2)));
  union { bf16x2_t v; unsigned u; } cv;
  cv.v = __builtin_amdgcn_cvt_pk_bf16_f32(a, b);
  return cv.u;
#else
  union { float f; unsigned u; } ua, ub; ua.f = a; ub.f = b;
  unsigned ra = ua.u + 0x7fffu + ((ua.u >> 16) & 1u);
  unsigned rb = ub.u + 0x7fffu + ((ub.u >> 16) & 1u);
  return __builtin_amdgcn_perm(rb, ra, 0x07060302u);
#endif
}

// dirty-hi f32x2 unpack of a bf16 pair: elem0 exact (d<<16), elem1 keeps the
// junk low 16 mantissa bits (rel err ~2^-16, far below the 2^-9 bf16 repack
// rounding). 1 VALU op per dword; blend chains on f32x2 emit v_pk_fma_f32.
__device__ __forceinline__ f32x2 up2d(unsigned d) {
  union { unsigned u; float f; } lo, hi;
  lo.u = d << 16; hi.u = d;
  return (f32x2){lo.f, hi.f};
}

// ws layout (bytes):
//   [0,     36864)  wOf bf16 [j:9][ks:2][q:4][m:32][i:8]  (A-frag order, m>=27 zero)
//   [36864, 110592) wA  bf16 [j:9][ks:2][q:4][o:64][i:8]  (A-frag order)

__global__ __launch_bounds__(256) void wprep(const float* __restrict__ w_off,
                                             const float* __restrict__ w_conv,
                                             short* __restrict__ wOf,
                                             short* __restrict__ wA) {
  int t = blockIdx.x * 256 + threadIdx.x;
  if (t < 36864) {
    int i = t & 7, o = (t >> 3) & 63, q = (t >> 9) & 3, ks = (t >> 11) & 1, j = t >> 12;
    int c = ks * 32 + q * 8 + i;
    wA[t] = f2bf(w_conv[o * 576 + c * 9 + j]);
  }
  if (t < 18432) {
    int i = t & 7, m = (t >> 3) & 31, q = (t >> 8) & 3, ks = (t >> 10) & 1, j = t >> 11;
    int c = ks * 32 + q * 8 + i;
    wOf[t] = (m < 27) ? f2bf(w_off[(m * 64 + c) * 9 + j]) : (short)0;
  }
}

// Fully fused: stage f32 NCHW -> bf16 NHWC halo tile in SWIZZLED LDS
// (zero-filled OOB, one barrier), offset conv (MFMA), shuffle-exchange
// offsets, LDS-gather sampling + MFMA GEMM (f32 global fallback for |o|>=1).
// Round-12 = round-10 dataflow (branch-local u32x4, wpe(4), no scratch) with
// 4x32 output tile: halo redundancy 3.75x -> 2.5x (33% less staging work
// per output), LDS 40960B -> exactly 4 blocks/CU = 32 waves/CU (HW max).
// Per-wave phase-1/3 code identical (each wave owns 16 px).
__global__ __launch_bounds__(512)
__attribute__((amdgpu_waves_per_eu(4)))
void dfuse(const float* __restrict__ x,
           const short* __restrict__ wOf,
           const float* __restrict__ b_off,
           const short* __restrict__ wA,
           float* __restrict__ out) {
  __shared__ __align__(16) unsigned lds_[TILEDW];

  int bi  = blockIdx.x & 7;        // XCD-aligned image index
  int tid = blockIdx.x >> 3;       // 0..127 tile within image
  int h0  = (tid >> 2) << 2;       // 0,4,..,124
  int w0  = (tid & 3) << 5;        // 0,32,64,96
  int t   = threadIdx.x;           // 0..511
  int wv  = t >> 6, l = t & 63;
  int col = l & 15, q = l >> 4;
  int px_local = wv * 16 + col;    // 0..127
  int rl  = px_local >> 5;         // local row 0..3
  int cl  = px_local & 31;         // local col 0..31
  int h   = h0 + rl;
  int w   = w0 + cl;
  int p   = h * HW_ + w;

  const float* xB = x + (size_t)bi * (CIN_ * IMG_);

  // ---- stage halo tile: rows h0-2..h0+5, cols w0-4..w0+35, 64 ch bf16 ----
  // unit u: cc = u%10 (4-px chunk), cq = (u/10)%8 (channels 8cq..8cq+7),
  // r = u/80 (0..7). Unit A = t (all 512), unit B = t+512 (first 128 only).
  // Write: one ds_write_b128 per pixel at swizzled chunk (cq ^ (c&7)).
  {
    f32x4 L0a[4], L1a[4], L0b[4], L1b[4];
    int baseA, baseB, swA, swB;
    unsigned ma, mb;
    {
      int u = t;
      int cc = u % 10, cq = (u / 10) & 7, r = u / 80;
      int y  = h0 - 2 + r;
      int ys = min(max(y, 0), HW_ - 1);
      int xg0 = w0 - 4 + cc * 4;
      int xs  = min(max(xg0, 0), HW_ - 4);             // 16B-aligned
      ma = ((y >= 0) && (y < HW_) && (xg0 >= 0) && (xg0 < HW_)) ? 0xffffffffu : 0u;
      const float* s0 = xB + (size_t)(8 * cq) * IMG_ + ys * HW_ + xs;
#pragma unroll
      for (int i = 0; i < 4; ++i) {
        L0a[i] = *(const f32x4*)(s0 + (2 * i) * IMG_);
        L1a[i] = *(const f32x4*)(s0 + (2 * i + 1) * IMG_);
      }
      baseA = (r * TC_ + cc * 4) * PIT_;
      swA   = cq ^ ((cc & 1) << 2);          // ^ pxi applied per store
    }
    bool hasB = (t + 512) < NU_;             // t < 128
    {
      int u = hasB ? (t + 512) : 0;
      int cc = u % 10, cq = (u / 10) & 7, r = u / 80;
      int y  = h0 - 2 + r;
      int ys = min(max(y, 0), HW_ - 1);
      int xg0 = w0 - 4 + cc * 4;
      int xs  = min(max(xg0, 0), HW_ - 4);
      mb = ((y >= 0) && (y < HW_) && (xg0 >= 0) && (xg0 < HW_)) ? 0xffffffffu : 0u;
      const float* s0 = xB + (size_t)(8 * cq) * IMG_ + ys * HW_ + xs;
#pragma unroll
      for (int i = 0; i < 4; ++i) {
        L0b[i] = *(const f32x4*)(s0 + (2 * i) * IMG_);
        L1b[i] = *(const f32x4*)(s0 + (2 * i + 1) * IMG_);
      }
      baseB = (r * TC_ + cc * 4) * PIT_;
      swB   = cq ^ ((cc & 1) << 2);
    }
#pragma unroll
    for (int pxi = 0; pxi < 4; ++pxi) {
      u32x4 v;
#pragma unroll
      for (int i = 0; i < 4; ++i) v[i] = PK2(L0a[i][pxi], L1a[i][pxi]) & ma;
      *(u32x4*)(lds_ + baseA + pxi * PIT_ + ((swA ^ pxi) << 2)) = v;
    }
    if (hasB) {
#pragma unroll
      for (int pxi = 0; pxi < 4; ++pxi) {
        u32x4 v;
#pragma unroll
        for (int i = 0; i < 4; ++i) v[i] = PK2(L0b[i][pxi], L1b[i][pxi]) & mb;
        *(u32x4*)(lds_ + baseB + pxi * PIT_ + ((swB ^ pxi) << 2)) = v;
      }
    }
  }
  __syncthreads();

  // ---- phase 1: offset conv from tile (tile is zero-padded: no masking) ----
  float oall[32];
  {
    const short* wq_ = wOf + q * 256 + col * 8;
    f32x4 a0v = {0.f, 0.f, 0.f, 0.f};
    f32x4 a1v = {0.f, 0.f, 0.f, 0.f};
    f32x4 a0w = {0.f, 0.f, 0.f, 0.f};
    f32x4 a1w = {0.f, 0.f, 0.f, 0.f};
    const unsigned* tbp = lds_ + ((rl + 2) * TC_ + (cl + 4)) * PIT_;
#pragma unroll
    for (int j = 0; j < 9; ++j) {
      int dy = j / 3 - 1, dx = j % 3 - 1;
      int ca = (q ^ ((cl + 4 + dx) & 7)) << 2;
      const unsigned* pb = tbp + (dy * TC_ + dx) * PIT_;
      union { u32x4 u; s16x8 v; } B0, B1;
      B0.u = *(const u32x4*)(pb + ca);
      B1.u = *(const u32x4*)(pb + (ca ^ 16));
      const short* wj = wq_ + j * 2048;
      s16x8 a00 = *(const s16x8*)(wj);
      s16x8 a01 = *(const s16x8*)(wj + 128);
      s16x8 a10 = *(const s16x8*)(wj + 1024);
      s16x8 a11 = *(const s16x8*)(wj + 1024 + 128);
      a0v = __builtin_amdgcn_mfma_f32_16x16x32_bf16(a00, B0.v, a0v, 0, 0, 0);
      a1v = __builtin_amdgcn_mfma_f32_16x16x32_bf16(a01, B0.v, a1v, 0, 0, 0);
      a0w = __builtin_amdgcn_mfma_f32_16x16x32_bf16(a10, B1.v, a0w, 0, 0, 0);
      a1w = __builtin_amdgcn_mfma_f32_16x16x32_bf16(a11, B1.v, a1w, 0, 0, 0);
    }
    a0v += a0w;
    a1v += a1w;
    // bias + sigmoid by producer lanes, then wave-local shuffle exchange
    float myv[8];
#pragma unroll
    for (int r = 0; r < 4; ++r) myv[r] = a0v[r] + b_off[q * 4 + r];
#pragma unroll
    for (int r = 0; r < 4; ++r) {
      int ch = 16 + q * 4 + r;
      float bo = b_off[min(ch, 26)];
      float v = a1v[r] + bo;
      myv[4 + r] = (ch >= 18) ? (1.f / (1.f + __expf(-v))) : v;
    }
#pragma unroll
    for (int qq = 0; qq < 4; ++qq) {
      int src = qq * 16 + col;
#pragma unroll
      for (int r = 0; r < 4; ++r) {
        oall[qq * 4 + r]      = __shfl(myv[r], src);
        oall[16 + qq * 4 + r] = __shfl(myv[4 + r], src);
      }
    }
  }

  // ---- phase 3: LDS-gather sampling + MFMA GEMM ----
  f32x4 acc[4], accB[4];
#pragma unroll
  for (int ms = 0; ms < 4; ++ms) {
    acc[ms]  = (f32x4){0.f, 0.f, 0.f, 0.f};
    accB[ms] = (f32x4){0.f, 0.f, 0.f, 0.f};
  }

  const short* wqA = wA + q * 512 + col * 8;

#pragma unroll
  for (int j = 0; j < 9; ++j) {
    float o1 = oall[j], o2 = oall[9 + j], mk = oall[18 + j];

    float pxf = o1 + (float)(w + (j % 3) - 1);
    float pyf = o2 + (float)(h + (j / 3) - 1);
    float fx = floorf(pxf), fy = floorf(pyf);
    int   x0 = (int)fx,   y0 = (int)fy;
    float ax = pxf - fx, ay = pyf - fy;
    float bx = 1.f - ax, by = 1.f - ay;

    // validity factorizes per-axis: zero the axis weight instead of the product
    bx = (x0 >= 0  && x0 < HW_)     ? bx : 0.f;
    ax = (x0 >= -1 && x0 < HW_ - 1) ? ax : 0.f;
    by = (y0 >= 0  && y0 < HW_)     ? by : 0.f;
    ay = (y0 >= -1 && y0 < HW_ - 1) ? ay : 0.f;
    float bym = by * mk, aym = ay * mk;
    float u00 = bym * bx, u01 = bym * ax;
    float u10 = aym * bx, u11 = aym * ax;
    f32x2 U00 = {u00, u00}, U01 = {u01, u01};
    f32x2 U10 = {u10, u10}, U11 = {u11, u11};

    unsigned F0u[4], F1u[4];
    bool intile = (o1 >= -1.f) && (o1 < 1.f) && (o2 >= -1.f) && (o2 < 1.f);
    if (intile) {
      // in-tile guarantee: r0 in [rl, rl+3] subset [0,6], c0 in [2,36] ->
      // no clamps; r1=r0+1 <= 7, c1 <= 37. Swizzled chunk addressing.
      // All u32x4 temporaries BRANCH-LOCAL (scratch-demotion fix, r10).
      int r0 = y0 - (h0 - 2), c0 = x0 - (w0 - 4);
      const unsigned* b00 = lds_ + (r0 * TC_ + c0) * PIT_;
      int s0 = (q ^ (c0 & 7)) << 2;
      int s1 = (q ^ ((c0 + 1) & 7)) << 2;
      u32x4 A00 = *(const u32x4*)(b00 + s0);
      u32x4 A01 = *(const u32x4*)(b00 + PIT_ + s1);
      u32x4 A10 = *(const u32x4*)(b00 + TC_ * PIT_ + s0);
      u32x4 A11 = *(const u32x4*)(b00 + TC_ * PIT_ + PIT_ + s1);
      u32x4 B00 = *(const u32x4*)(b00 + (s0 ^ 16));
      u32x4 B01 = *(const u32x4*)(b00 + PIT_ + (s1 ^ 16));
      u32x4 B10 = *(const u32x4*)(b00 + TC_ * PIT_ + (s0 ^ 16));
      u32x4 B11 = *(const u32x4*)(b00 + TC_ * PIT_ + PIT_ + (s1 ^ 16));
#pragma unroll
      for (int i = 0; i < 4; ++i) {
        f32x2 v0 = up2d(A00[i]) * U00 + up2d(A01[i]) * U01
                 + up2d(A10[i]) * U10 + up2d(A11[i]) * U11;   // v_pk_fma_f32
        F0u[i] = PK2(v0.x, v0.y);
        f32x2 v1 = up2d(B00[i]) * U00 + up2d(B01[i]) * U01
                 + up2d(B10[i]) * U10 + up2d(B11[i]) * U11;
        F1u[i] = PK2(v1.x, v1.y);
      }
    } else {
      // rare fallback: gather straight from f32 NCHW x (clamps only here)
      int xc0 = min(max(x0, 0), HW_ - 1), xc1 = min(max(x0 + 1, 0), HW_ - 1);
      int yc0 = min(max(y0, 0), HW_ - 1), yc1 = min(max(y0 + 1, 0), HW_ - 1);
      int g00 = yc0 * HW_ + xc0, g01 = yc0 * HW_ + xc1;
      int g10 = yc1 * HW_ + xc0, g11 = yc1 * HW_ + xc1;
      for (int hB = 0; hB < 2; ++hB) {
        for (int ii = 0; ii < 4; ++ii) {
          int c0i = hB * 32 + q * 8 + 2 * ii;
          const float* pc = xB + c0i * IMG_;
          const float* pd = pc + IMG_;
          float va = u00 * pc[g00] + u01 * pc[g01] + u10 * pc[g10] + u11 * pc[g11];
          float vb = u00 * pd[g00] + u01 * pd[g01] + u10 * pd[g10] + u11 * pd[g11];
          if (hB) F1u[ii] = PK2(va, vb); else F0u[ii] = PK2(va, vb);
        }
      }
    }

    union { unsigned u[4]; s16x8 v; } F0, F1;
#pragma unroll
    for (int i = 0; i < 4; ++i) { F0.u[i] = F0u[i]; F1.u[i] = F1u[i]; }

    const short* wj = wqA + j * 4096;
#pragma unroll
    for (int ms = 0; ms < 4; ++ms) {
      s16x8 a0 = *(const s16x8*)(wj + ms * 128);
      acc[ms] = __builtin_amdgcn_mfma_f32_16x16x32_bf16(a0, F0.v, acc[ms], 0, 0, 0);
    }
#pragma unroll
    for (int ms = 0; ms < 4; ++ms) {
      s16x8 a1 = *(const s16x8*)(wj + 2048 + ms * 128);
      accB[ms] = __builtin_amdgcn_mfma_f32_16x16x32_bf16(a1, F1.v, accB[ms], 0, 0, 0);
    }
  }

  float* op = out + (size_t)bi * (CIN_ * IMG_) + p;
#pragma unroll
  for (int ms = 0; ms < 4; ++ms) {
    f32x4 r = acc[ms] + accB[ms];
#pragma unroll
    for (int rr = 0; rr < 4; ++rr)
      op[(ms * 16 + q * 4 + rr) * IMG_] = r[rr];
  }
}

extern "C" void kernel_launch(void* const* d_in, const int* in_sizes, int n_in,
                              void* d_out, int out_size, void* d_ws, size_t ws_size,
                              hipStream_t stream) {
  const float* x      = (const float*)d_in[0];
  const float* w_off  = (const float*)d_in[1];
  const float* b_off  = (const float*)d_in[2];
  const float* w_conv = (const float*)d_in[3];
  float* out = (float*)d_out;

  char* ws = (char*)d_ws;
  short* wOf = (short*)(ws);
  short* wA  = (short*)(ws + 36864);

  hipLaunchKernelGGL(wprep, dim3(144),  dim3(256), 0, stream, w_off, w_conv, wOf, wA);
  hipLaunchKernelGGL(dfuse, dim3(1024), dim3(512), 0, stream, x, wOf, b_off, wA, out);
}

// Round 13
// 126.741 us; speedup vs baseline: 1.0579x; 1.0086x over previous
//
#include <hip/hip_runtime.h>
#include <math.h>

#define HW_   128
#define CIN_  64
#define IMG_  (HW_ * HW_)       // 16384

// 2 output rows x 32 output cols per block
#define TR_    6                // tile rows  [h0-2 .. h0+3]
#define TC_    40               // tile cols  [w0-4 .. w0+35]
#define PIT_   36               // dwords per pixel (64ch bf16 = 32 dw + 4 pad)
                                // MUST be mult of 4: keeps every u32x4 LDS access 16B-aligned
#define TILEDW (TR_ * TC_ * PIT_)   // 8640 dw = 34560 B -> 4 blocks/CU
#define NU_    (TR_ * 8 * 10)       // 480 staging units (r, cq, cc)

typedef short    s16x8 __attribute__((ext_vector_type(8)));
typedef float    f32x4 __attribute__((ext_vector_type(4)));
typedef float    f32x2 __attribute__((ext_vector_type(2)));
typedef unsigned u32x4 __attribute__((ext_vector_type(4)));

__device__ __forceinline__ short f2bf(float f) {
  union { float f; unsigned i; } v; v.f = f;
  unsigned r = (v.i + 0x7fffu + ((v.i >> 16) & 1u)) >> 16;   // RNE
  return (short)r;
}

#if defined(__has_builtin)
#if __has_builtin(__builtin_amdgcn_cvt_pk_bf16_f32)
#define HAVE_CVT_PK_BF16 1
#endif
#endif

// pack two f32 -> bf16 pair (lo=a, hi=b)
__device__ __forceinline__ unsigned PK2(float a, float b) {
#ifdef HAVE_CVT_PK_BF16
  typedef __bf16 bf16x2_t __attribute__((ext_vector_type(2)));
  union { bf16x2_t v; unsigned u; } cv;
  cv.v = __builtin_amdgcn_cvt_pk_bf16_f32(a, b);
  return cv.u;
#else
  union { float f; unsigned u; } ua, ub; ua.f = a; ub.f = b;
  unsigned ra = ua.u + 0x7fffu + ((ua.u >> 16) & 1u);
  unsigned rb = ub.u + 0x7fffu + ((ub.u >> 16) & 1u);
  return __builtin_amdgcn_perm(rb, ra, 0x07060302u);
#endif
}

// dirty-hi f32x2 unpack of a bf16 pair: elem0 exact (d<<16), elem1 keeps the
// junk low 16 mantissa bits (rel err ~2^-16, far below the 2^-9 bf16 repack
// rounding). 1 VALU op per dword; blend chains on f32x2 emit v_pk_fma_f32.
__device__ __forceinline__ f32x2 up2d(unsigned d) {
  union { unsigned u; float f; } lo, hi;
  lo.u = d << 16; hi.u = d;
  return (f32x2){lo.f, hi.f};
}

// ws layout (bytes):
//   [0,     36864)  wOf bf16 [j:9][ks:2][q:4][m:32][i:8]  (A-frag order, m>=27 zero)
//   [36864, 110592) wA  bf16 [j:9][ks:2][q:4][o:64][i:8]  (A-frag order)

__global__ __launch_bounds__(256) void wprep(const float* __restrict__ w_off,
                                             const float* __restrict__ w_conv,
                                             short* __restrict__ wOf,
                                             short* __restrict__ wA) {
  int t = blockIdx.x * 256 + threadIdx.x;
  if (t < 36864) {
    int i = t & 7, o = (t >> 3) & 63, q = (t >> 9) & 3, ks = (t >> 11) & 1, j = t >> 12;
    int c = ks * 32 + q * 8 + i;
    wA[t] = f2bf(w_conv[o * 576 + c * 9 + j]);
  }
  if (t < 18432) {
    int i = t & 7, m = (t >> 3) & 31, q = (t >> 8) & 3, ks = (t >> 10) & 1, j = t >> 11;
    int c = ks * 32 + q * 8 + i;
    wOf[t] = (m < 27) ? f2bf(w_off[(m * 64 + c) * 9 + j]) : (short)0;
  }
}

// Fully fused (best measured configuration, session round 7):
// stage f32 NCHW -> bf16 NHWC halo tile in LDS (zero-filled OOB, one barrier),
// offset conv (MFMA), shuffle-exchange offsets, LDS-gather sampling + MFMA
// GEMM (f32 global fallback for |o|>=1).
// Key decisions (each counter-verified this session):
//  - PIT_=36 (mult of 4): every u32x4 LDS access 16B-aligned. PIT_=35 broke
//    alignment (+30us); PIT_=32+swizzle variants measured equal, not better.
//  - 2x32 tile: 4x16 hurt store coalescing (WRITE 33->37MB); 4x32 (2.5x halo)
//    measured equal. XCD swizzle bi=blockIdx&7: FETCH 118->17MB (unique-bound).
//  - staging unit = (row, channel-QUAD, 4-px chunk): one ds_write_b128/pixel,
//    T14-batched loads (all 16 float4 issued before converts).
//  - branch-local u32x4 only (partial-def across divergent branch -> scratch
//    in HBM, +25MB phantom WRITE); waves_per_eu(4) (wpe(5) caps VGPR=48 ->
//    64-VGPR staging batch spills).
//  - split MFMA accumulator banks; packed f32x2 blend; dirty-hi unpack.
// Plateau: latency-bound at ~57us, no pipe >50% (VALU~26us, LDS~16us,
// MFMA~6us, HBM 11%); occupancy/ILP/conflict/halo levers all probed to null.
__global__ __launch_bounds__(256)
__attribute__((amdgpu_waves_per_eu(4)))
void dfuse(const float* __restrict__ x,
           const short* __restrict__ wOf,
           const float* __restrict__ b_off,
           const short* __restrict__ wA,
           float* __restrict__ out) {
  __shared__ __align__(16) unsigned lds_[TILEDW];

  int bi  = blockIdx.x & 7;        // XCD-aligned image index
  int tid = blockIdx.x >> 3;       // 0..255 tile within image
  int h0  = (tid >> 2) << 1;       // 0,2,..,126
  int w0  = (tid & 3) << 5;        // 0,32,64,96
  int t   = threadIdx.x;
  int wv  = t >> 6, l = t & 63;
  int col = l & 15, q = l >> 4;
  int px_local = wv * 16 + col;    // 0..63
  int rl  = px_local >> 5;         // local row 0..1
  int cl  = px_local & 31;         // local col 0..31
  int h   = h0 + rl;
  int w   = w0 + cl;
  int p   = h * HW_ + w;

  const float* xB = x + (size_t)bi * (CIN_ * IMG_);

  // ---- stage halo tile: rows h0-2..h0+3, cols w0-4..w0+35, 64 ch bf16 ----
  // unit u: cc = u%10 (4-px chunk), cq = (u/10)%8 (channels 8cq..8cq+7),
  // r = u/80. Unit A = t, unit B = t+256 (first 224 threads only).
  {
    f32x4 L0a[4], L1a[4], L0b[4], L1b[4];
    int sda, sdb;
    unsigned ma, mb;
    {
      int u = t;
      int cc = u % 10, cq = (u / 10) & 7, r = u / 80;
      int y  = h0 - 2 + r;
      int ys = min(max(y, 0), HW_ - 1);
      int xg0 = w0 - 4 + cc * 4;
      int xs  = min(max(xg0, 0), HW_ - 4);             // 16B-aligned
      ma = ((y >= 0) && (y < HW_) && (xg0 >= 0) && (xg0 < HW_)) ? 0xffffffffu : 0u;
      const float* s0 = xB + (size_t)(8 * cq) * IMG_ + ys * HW_ + xs;
#pragma unroll
      for (int i = 0; i < 4; ++i) {
        L0a[i] = *(const f32x4*)(s0 + (2 * i) * IMG_);
        L1a[i] = *(const f32x4*)(s0 + (2 * i + 1) * IMG_);
      }
      sda = (r * TC_ + cc * 4) * PIT_ + cq * 4;
    }
    bool hasB = (t + 256) < NU_;
    {
      int u = hasB ? (t + 256) : 0;
      int cc = u % 10, cq = (u / 10) & 7, r = u / 80;
      int y  = h0 - 2 + r;
      int ys = min(max(y, 0), HW_ - 1);
      int xg0 = w0 - 4 + cc * 4;
      int xs  = min(max(xg0, 0), HW_ - 4);
      mb = ((y >= 0) && (y < HW_) && (xg0 >= 0) && (xg0 < HW_)) ? 0xffffffffu : 0u;
      const float* s0 = xB + (size_t)(8 * cq) * IMG_ + ys * HW_ + xs;
#pragma unroll
      for (int i = 0; i < 4; ++i) {
        L0b[i] = *(const f32x4*)(s0 + (2 * i) * IMG_);
        L1b[i] = *(const f32x4*)(s0 + (2 * i + 1) * IMG_);
      }
      sdb = (r * TC_ + cc * 4) * PIT_ + cq * 4;
    }
#pragma unroll
    for (int pxi = 0; pxi < 4; ++pxi) {
      u32x4 v;
#pragma unroll
      for (int i = 0; i < 4; ++i) v[i] = PK2(L0a[i][pxi], L1a[i][pxi]) & ma;
      *(u32x4*)(lds_ + sda + pxi * PIT_) = v;
    }
    if (hasB) {
#pragma unroll
      for (int pxi = 0; pxi < 4; ++pxi) {
        u32x4 v;
#pragma unroll
        for (int i = 0; i < 4; ++i) v[i] = PK2(L0b[i][pxi], L1b[i][pxi]) & mb;
        *(u32x4*)(lds_ + sdb + pxi * PIT_) = v;
      }
    }
  }
  __syncthreads();

  // ---- phase 1: offset conv from tile (tile is zero-padded: no masking) ----
  float oall[32];
  {
    const short* wq = wOf + q * 256 + col * 8;
    f32x4 a0v = {0.f, 0.f, 0.f, 0.f};
    f32x4 a1v = {0.f, 0.f, 0.f, 0.f};
    f32x4 a0w = {0.f, 0.f, 0.f, 0.f};
    f32x4 a1w = {0.f, 0.f, 0.f, 0.f};
    const unsigned* tb = &lds_[((rl + 2) * TC_ + (cl + 4)) * PIT_ + q * 4];
#pragma unroll
    for (int j = 0; j < 9; ++j) {
      int dy = j / 3 - 1, dx = j % 3 - 1;
      const unsigned* tp = tb + (dy * TC_ + dx) * PIT_;   // compile-time imm
      union { u32x4 u; s16x8 v; } B0, B1;
      B0.u = *(const u32x4*)tp;
      B1.u = *(const u32x4*)(tp + 16);
      const short* wj = wq + j * 2048;
      s16x8 a00 = *(const s16x8*)(wj);
      s16x8 a01 = *(const s16x8*)(wj + 128);
      s16x8 a10 = *(const s16x8*)(wj + 1024);
      s16x8 a11 = *(const s16x8*)(wj + 1024 + 128);
      a0v = __builtin_amdgcn_mfma_f32_16x16x32_bf16(a00, B0.v, a0v, 0, 0, 0);
      a1v = __builtin_amdgcn_mfma_f32_16x16x32_bf16(a01, B0.v, a1v, 0, 0, 0);
      a0w = __builtin_amdgcn_mfma_f32_16x16x32_bf16(a10, B1.v, a0w, 0, 0, 0);
      a1w = __builtin_amdgcn_mfma_f32_16x16x32_bf16(a11, B1.v, a1w, 0, 0, 0);
    }
    a0v += a0w;
    a1v += a1w;
    // bias + sigmoid by producer lanes, then wave-local shuffle exchange
    float myv[8];
#pragma unroll
    for (int r = 0; r < 4; ++r) myv[r] = a0v[r] + b_off[q * 4 + r];
#pragma unroll
    for (int r = 0; r < 4; ++r) {
      int ch = 16 + q * 4 + r;
      float bo = b_off[min(ch, 26)];
      float v = a1v[r] + bo;
      myv[4 + r] = (ch >= 18) ? (1.f / (1.f + __expf(-v))) : v;
    }
#pragma unroll
    for (int qq = 0; qq < 4; ++qq) {
      int src = qq * 16 + col;
#pragma unroll
      for (int r = 0; r < 4; ++r) {
        oall[qq * 4 + r]      = __shfl(myv[r], src);
        oall[16 + qq * 4 + r] = __shfl(myv[4 + r], src);
      }
    }
  }

  // ---- phase 3: LDS-gather sampling + MFMA GEMM ----
  f32x4 acc[4], accB[4];
#pragma unroll
  for (int ms = 0; ms < 4; ++ms) {
    acc[ms]  = (f32x4){0.f, 0.f, 0.f, 0.f};
    accB[ms] = (f32x4){0.f, 0.f, 0.f, 0.f};
  }

  const short* wqA = wA + q * 512 + col * 8;

#pragma unroll
  for (int j = 0; j < 9; ++j) {
    float o1 = oall[j], o2 = oall[9 + j], mk = oall[18 + j];

    float pxf = o1 + (float)(w + (j % 3) - 1);
    float pyf = o2 + (float)(h + (j / 3) - 1);
    float fx = floorf(pxf), fy = floorf(pyf);
    int   x0 = (int)fx,   y0 = (int)fy;
    float ax = pxf - fx, ay = pyf - fy;
    float bx = 1.f - ax, by = 1.f - ay;

    // validity factorizes per-axis: zero the axis weight instead of the product
    bx = (x0 >= 0  && x0 < HW_)     ? bx : 0.f;
    ax = (x0 >= -1 && x0 < HW_ - 1) ? ax : 0.f;
    by = (y0 >= 0  && y0 < HW_)     ? by : 0.f;
    ay = (y0 >= -1 && y0 < HW_ - 1) ? ay : 0.f;
    float bym = by * mk, aym = ay * mk;
    float u00 = bym * bx, u01 = bym * ax;
    float u10 = aym * bx, u11 = aym * ax;
    f32x2 U00 = {u00, u00}, U01 = {u01, u01};
    f32x2 U10 = {u10, u10}, U11 = {u11, u11};

    unsigned F0u[4], F1u[4];
    bool intile = (o1 >= -1.f) && (o1 < 1.f) && (o2 >= -1.f) && (o2 < 1.f);
    if (intile) {
      // in-tile guarantee: r0 in [0,4], c0 in [2,36] -> no clamps; r1=r0+1,
      // c1=c0+1 -> all 8 reads are one base + compile-time immediates.
      // 16B alignment holds: (r0*TC_+c0)*PIT_ + q*4 is a multiple of 4 dw.
      int r0 = y0 - (h0 - 2), c0 = x0 - (w0 - 4);
      const unsigned* t00 = &lds_[(r0 * TC_ + c0) * PIT_ + q * 4];
      u32x4 A00 = *(const u32x4*)(t00);
      u32x4 A01 = *(const u32x4*)(t00 + PIT_);
      u32x4 A10 = *(const u32x4*)(t00 + TC_ * PIT_);
      u32x4 A11 = *(const u32x4*)(t00 + TC_ * PIT_ + PIT_);
      u32x4 B00 = *(const u32x4*)(t00 + 16);
      u32x4 B01 = *(const u32x4*)(t00 + PIT_ + 16);
      u32x4 B10 = *(const u32x4*)(t00 + TC_ * PIT_ + 16);
      u32x4 B11 = *(const u32x4*)(t00 + TC_ * PIT_ + PIT_ + 16);
#pragma unroll
      for (int i = 0; i < 4; ++i) {
        f32x2 v0 = up2d(A00[i]) * U00 + up2d(A01[i]) * U01
                 + up2d(A10[i]) * U10 + up2d(A11[i]) * U11;   // v_pk_fma_f32
        F0u[i] = PK2(v0.x, v0.y);
        f32x2 v1 = up2d(B00[i]) * U00 + up2d(B01[i]) * U01
                 + up2d(B10[i]) * U10 + up2d(B11[i]) * U11;
        F1u[i] = PK2(v1.x, v1.y);
      }
    } else {
      // rare fallback: gather straight from f32 NCHW x (clamps only here)
      int xc0 = min(max(x0, 0), HW_ - 1), xc1 = min(max(x0 + 1, 0), HW_ - 1);
      int yc0 = min(max(y0, 0), HW_ - 1), yc1 = min(max(y0 + 1, 0), HW_ - 1);
      int g00 = yc0 * HW_ + xc0, g01 = yc0 * HW_ + xc1;
      int g10 = yc1 * HW_ + xc0, g11 = yc1 * HW_ + xc1;
      for (int hB = 0; hB < 2; ++hB) {
        for (int ii = 0; ii < 4; ++ii) {
          int c0i = hB * 32 + q * 8 + 2 * ii;
          const float* pc = xB + c0i * IMG_;
          const float* pd = pc + IMG_;
          float va = u00 * pc[g00] + u01 * pc[g01] + u10 * pc[g10] + u11 * pc[g11];
          float vb = u00 * pd[g00] + u01 * pd[g01] + u10 * pd[g10] + u11 * pd[g11];
          if (hB) F1u[ii] = PK2(va, vb); else F0u[ii] = PK2(va, vb);
        }
      }
    }

    union { unsigned u[4]; s16x8 v; } F0, F1;
#pragma unroll
    for (int i = 0; i < 4; ++i) { F0.u[i] = F0u[i]; F1.u[i] = F1u[i]; }

    const short* wj = wqA + j * 4096;
#pragma unroll
    for (int ms = 0; ms < 4; ++ms) {
      s16x8 a0 = *(const s16x8*)(wj + ms * 128);
      acc[ms] = __builtin_amdgcn_mfma_f32_16x16x32_bf16(a0, F0.v, acc[ms], 0, 0, 0);
    }
#pragma unroll
    for (int ms = 0; ms < 4; ++ms) {
      s16x8 a1 = *(const s16x8*)(wj + 2048 + ms * 128);
      accB[ms] = __builtin_amdgcn_mfma_f32_16x16x32_bf16(a1, F1.v, accB[ms], 0, 0, 0);
    }
  }

  float* op = out + (size_t)bi * (CIN_ * IMG_) + p;
#pragma unroll
  for (int ms = 0; ms < 4; ++ms) {
    f32x4 r = acc[ms] + accB[ms];
#pragma unroll
    for (int rr = 0; rr < 4; ++rr)
      op[(ms * 16 + q * 4 + rr) * IMG_] = r[rr];
  }
}

extern "C" void kernel_launch(void* const* d_in, const int* in_sizes, int n_in,
                              void* d_out, int out_size, void* d_ws, size_t ws_size,
                              hipStream_t stream) {
  const float* x      = (const float*)d_in[0];
  const float* w_off  = (const float*)d_in[1];
  const float* b_off  = (const float*)d_in[2];
  const float* w_conv = (const float*)d_in[3];
  float* out = (float*)d_out;

  char* ws = (char*)d_ws;
  short* wOf = (short*)(ws);
  short* wA  = (short*)(ws + 36864);

  hipLaunchKernelGGL(wprep, dim3(144),  dim3(256), 0, stream, w_off, w_conv, wOf, wA);
  hipLaunchKernelGGL(dfuse, dim3(2048), dim3(256), 0, stream, x, wOf, b_off, wA, out);
}